// Round 1
// baseline (381.101 us; speedup 1.0000x reference)
//
#include <hip/hip_runtime.h>

// Problem constants (from reference):
//   data: [4, 3, 1024, 1024] fp32; NX=64, scale=16, ny=64, N=4096, p=15
//   out = concat(A[4,4096,4096], data) flat fp32
#define BB 4
#define CC 3
#define HH 1024
#define WW 1024
#define NXG 64
#define NYG 64
#define SCALE 16
#define PP 15
#define NNODE 4096                        // NXG*NYG

static const long long A_ELEMS    = (long long)BB * NNODE * NNODE;   // 67,108,864
static const long long DATA_ELEMS = (long long)BB * CC * HH * WW;    // 12,582,912

// Pass 1: zero the A region and copy data into the tail, vectorized float4.
__global__ void zero_copy_kernel(const float4* __restrict__ data,
                                 float4* __restrict__ out,
                                 long long a_vec, long long total_vec) {
    long long i = (long long)blockIdx.x * blockDim.x + threadIdx.x;
    long long stride = (long long)gridDim.x * blockDim.x;
    const float4 z = make_float4(0.f, 0.f, 0.f, 0.f);
    for (; i < total_vec; i += stride) {
        if (i < a_vec) {
            out[i] = z;
        } else {
            out[i] = data[i - a_vec];
        }
    }
}

// Pass 2: one wave (64 lanes) per edge. Edge value = sum over c in [0,3),
// (i,j) in [0,15)^2 of |pixA - pixB| for the two adjacent grid-cell
// sub-patches. Lane 0 scatters the symmetric pair into A.
__global__ void edge_kernel(const float* __restrict__ data,
                            float* __restrict__ A) {
    const int NV = BB * (NYG - 1) * NXG;  // 16128 vertical edges
    const int NH = BB * NYG * (NXG - 1);  // 16128 horizontal edges

    int wave = blockIdx.x * (blockDim.x >> 6) + (threadIdx.x >> 6);
    int lane = threadIdx.x & 63;
    if (wave >= NV + NH) return;

    float s = 0.f;
    int b, row_lo, row_hi, col_lo, col_hi;   // node coords of the two cells
    const float* p0;
    long long delta;  // p1 = p0 + delta

    if (wave < NV) {
        // vertical edge: cells (y, x) and (y+1, x)
        int e   = wave;
        b       = e / ((NYG - 1) * NXG);
        int rem = e % ((NYG - 1) * NXG);
        int y   = rem / NXG;
        int x   = rem % NXG;
        p0 = data + (((long long)(b * CC) * HH + (long long)y * SCALE) * WW
                     + (long long)x * SCALE);
        delta = (long long)SCALE * WW;     // next grid row
        row_lo = y;     col_lo = x;
        row_hi = y + 1; col_hi = x;
    } else {
        // horizontal edge: cells (y, x) and (y, x+1)
        int e   = wave - NV;
        b       = e / (NYG * (NXG - 1));
        int rem = e % (NYG * (NXG - 1));
        int y   = rem / (NXG - 1);
        int x   = rem % (NXG - 1);
        p0 = data + (((long long)(b * CC) * HH + (long long)y * SCALE) * WW
                     + (long long)x * SCALE);
        delta = SCALE;                     // next grid col
        row_lo = y; col_lo = x;
        row_hi = y; col_hi = x + 1;
    }

    const long long chan_stride = (long long)HH * WW;
    for (int c = 0; c < CC; ++c) {
        const float* base0 = p0 + (long long)c * chan_stride;
        const float* base1 = base0 + delta;
        for (int t = lane; t < PP * PP; t += 64) {
            int i = t / PP;
            int j = t - i * PP;
            long long off = (long long)i * WW + j;
            s += fabsf(base1[off] - base0[off]);
        }
    }

    // 64-lane reduction
    #pragma unroll
    for (int off = 32; off > 0; off >>= 1)
        s += __shfl_down(s, off, 64);

    if (lane == 0) {
        int n_lo = row_lo * NXG + col_lo;
        int n_hi = row_hi * NXG + col_hi;
        long long baseA = (long long)b * NNODE * NNODE;
        A[baseA + (long long)n_hi * NNODE + n_lo] = s;  // e.g. lower->upper
        A[baseA + (long long)n_lo * NNODE + n_hi] = s;  // upper->lower
    }
}

extern "C" void kernel_launch(void* const* d_in, const int* in_sizes, int n_in,
                              void* d_out, int out_size, void* d_ws, size_t ws_size,
                              hipStream_t stream) {
    const float* data = (const float*)d_in[0];
    float* out = (float*)d_out;

    const long long a_vec = A_ELEMS / 4;
    const long long total_vec = (A_ELEMS + DATA_ELEMS) / 4;  // 19,922,944

    // Pass 1: zero A + copy data (whole d_out written every call).
    zero_copy_kernel<<<8192, 256, 0, stream>>>((const float4*)data,
                                               (float4*)out, a_vec, total_vec);

    // Pass 2: fill edges. 32256 edges, 4 waves/block -> 8064 blocks.
    const int n_edges = BB * (NYG - 1) * NXG + BB * NYG * (NXG - 1);
    const int waves_per_block = 256 / 64;
    const int blocks = (n_edges + waves_per_block - 1) / waves_per_block;
    edge_kernel<<<blocks, 256, 0, stream>>>(data, out);
}

// Round 2
// 365.035 us; speedup vs baseline: 1.0440x; 1.0440x over previous
//
#include <hip/hip_runtime.h>

// data: [4, 3, 1024, 1024] fp32; NX=64, scale=16, ny=64, N=4096, p=15
// out = concat(A[4,4096,4096], data) flat fp32
#define BB 4
#define CC 3
#define HH 1024
#define WW 1024
#define NXG 64
#define NYG 64
#define SCALE 16
#define PP 15
#define NNODE 4096

static const long long A_ELEMS    = (long long)BB * NNODE * NNODE;   // 67,108,864
static const long long DATA_ELEMS = (long long)BB * CC * HH * WW;    // 12,582,912

#define ROW_BLOCKS 4096    // 4 waves/block -> 16384 row-waves (= BB*NNODE)
#define COPY_BLOCKS 1024   // grid-stride copy of data into out tail

// One wave per A-row: compute the row's <=4 edge affinities (each edge is
// computed redundantly by both endpoint rows -> no inter-block ordering
// needed), then stream the 4096-float row (zeros + inserted edge values).
// Remaining blocks copy `data` to the output tail.
__global__ __launch_bounds__(256) void fused_kernel(const float* __restrict__ data,
                                                    float* __restrict__ out) {
    if (blockIdx.x < ROW_BLOCKS) {
        const int wid  = blockIdx.x * 4 + (threadIdx.x >> 6);  // 0..16383
        const int lane = threadIdx.x & 63;
        const int b = wid >> 12;          // batch
        const int n = wid & (NNODE - 1);  // node / A-row
        const int y = n >> 6;
        const int x = n & 63;

        const int r = lane >> 2;   // patch row 0..15 (15 inactive)
        const int q = lane & 3;    // float4 quad within the 16-wide cell
        const bool active = (r < PP);

        const bool hasUp = y > 0, hasDown = y < NYG - 1;
        const bool hasLeft = x > 0, hasRight = x < NXG - 1;

        // cell (y, x), channel 0, top-left pixel
        const float* cell = data + (((long long)(b * CC)) * HH + (long long)y * SCALE) * WW
                                 + x * SCALE;
        const long long CH = (long long)HH * WW;

        float sUp = 0.f, sDown = 0.f, sLeft = 0.f, sRight = 0.f;
        if (active) {
            #pragma unroll
            for (int c = 0; c < CC; ++c) {
                const float* p = cell + (long long)c * CH + (long long)r * WW + q * 4;
                const float4 cf = *(const float4*)p;
                const bool keepW = (q != 3);  // quad 3 covers cols 12..15; col 15 excluded
                if (hasUp) {
                    float4 nf = *(const float4*)(p - (long long)SCALE * WW);
                    float d = fabsf(nf.x - cf.x) + fabsf(nf.y - cf.y) + fabsf(nf.z - cf.z);
                    if (keepW) d += fabsf(nf.w - cf.w);
                    sUp += d;
                }
                if (hasDown) {
                    float4 nf = *(const float4*)(p + (long long)SCALE * WW);
                    float d = fabsf(nf.x - cf.x) + fabsf(nf.y - cf.y) + fabsf(nf.z - cf.z);
                    if (keepW) d += fabsf(nf.w - cf.w);
                    sDown += d;
                }
                if (hasLeft) {
                    float4 nf = *(const float4*)(p - SCALE);
                    float d = fabsf(nf.x - cf.x) + fabsf(nf.y - cf.y) + fabsf(nf.z - cf.z);
                    if (keepW) d += fabsf(nf.w - cf.w);
                    sLeft += d;
                }
                if (hasRight) {
                    float4 nf = *(const float4*)(p + SCALE);
                    float d = fabsf(nf.x - cf.x) + fabsf(nf.y - cf.y) + fabsf(nf.z - cf.z);
                    if (keepW) d += fabsf(nf.w - cf.w);
                    sRight += d;
                }
            }
        }

        // 64-lane butterfly reductions (all lanes end with the totals)
        #pragma unroll
        for (int off = 1; off < 64; off <<= 1) {
            sUp    += __shfl_xor(sUp, off, 64);
            sDown  += __shfl_xor(sDown, off, 64);
            sLeft  += __shfl_xor(sLeft, off, 64);
            sRight += __shfl_xor(sRight, off, 64);
        }

        const int cUp    = hasUp    ? n - NXG : -1;
        const int cDown  = hasDown  ? n + NXG : -1;
        const int cLeft  = hasLeft  ? n - 1   : -1;
        const int cRight = hasRight ? n + 1   : -1;

        float4* rowp = (float4*)(out + (long long)b * NNODE * NNODE + (long long)n * NNODE);
        #pragma unroll
        for (int k = 0; k < 16; ++k) {
            const int f = k * 64 + lane;       // float4 index in row (coalesced)
            const int c0 = f * 4;
            float4 v;
            v.x = (c0   == cUp) ? sUp : (c0   == cLeft) ? sLeft : (c0   == cRight) ? sRight : (c0   == cDown) ? sDown : 0.f;
            v.y = (c0+1 == cUp) ? sUp : (c0+1 == cLeft) ? sLeft : (c0+1 == cRight) ? sRight : (c0+1 == cDown) ? sDown : 0.f;
            v.z = (c0+2 == cUp) ? sUp : (c0+2 == cLeft) ? sLeft : (c0+2 == cRight) ? sRight : (c0+2 == cDown) ? sDown : 0.f;
            v.w = (c0+3 == cUp) ? sUp : (c0+3 == cLeft) ? sLeft : (c0+3 == cRight) ? sRight : (c0+3 == cDown) ? sDown : 0.f;
            rowp[f] = v;
        }
    } else {
        // copy data -> out tail, float4, branch-free grid-stride
        long long i = (long long)(blockIdx.x - ROW_BLOCKS) * blockDim.x + threadIdx.x;
        const long long stride = (long long)COPY_BLOCKS * blockDim.x;
        const float4* __restrict__ src = (const float4*)data;
        float4* __restrict__ dst = (float4*)(out + A_ELEMS);
        const long long nvec = DATA_ELEMS / 4;
        for (; i < nvec; i += stride) dst[i] = src[i];
    }
}

extern "C" void kernel_launch(void* const* d_in, const int* in_sizes, int n_in,
                              void* d_out, int out_size, void* d_ws, size_t ws_size,
                              hipStream_t stream) {
    const float* data = (const float*)d_in[0];
    float* out = (float*)d_out;
    fused_kernel<<<ROW_BLOCKS + COPY_BLOCKS, 256, 0, stream>>>(data, out);
}

// Round 4
// 360.089 us; speedup vs baseline: 1.0584x; 1.0137x over previous
//
#include <hip/hip_runtime.h>

// data: [4, 3, 1024, 1024] fp32; NX=64, scale=16, ny=64, N=4096, p=15
// out = concat(A[4,4096,4096], data) flat fp32
#define BB 4
#define CC 3
#define HH 1024
#define WW 1024
#define NXG 64
#define NYG 64
#define SCALE 16
#define PP 15
#define NNODE 4096

static const long long A_ELEMS    = (long long)BB * NNODE * NNODE;   // 67,108,864
static const long long DATA_ELEMS = (long long)BB * CC * HH * WW;    // 12,582,912

#define NV_PER_B 4032          // 63*64 vertical edges per batch
#define NH_PER_B 4032          // 64*63 horizontal edges per batch
#define NV_TOT   16128         // BB * NV_PER_B
#define NE_TOT   32256

#define K1_COPY_BLOCKS 512
#define K1_EDGE_BLOCKS 8064    // 32256 edge-waves / 4 per block

// Kernel 1: [0,512) blocks copy data -> out tail; the rest compute one edge
// affinity per wave into ws[edge]. Both read `data`, sharing L2/L3 fetch.
__global__ __launch_bounds__(256) void edge_copy_kernel(const float* __restrict__ data,
                                                        float* __restrict__ ws,
                                                        float* __restrict__ out) {
    if (blockIdx.x < K1_COPY_BLOCKS) {
        long long i = (long long)blockIdx.x * 256 + threadIdx.x;
        const long long stride = (long long)K1_COPY_BLOCKS * 256;
        const float4* __restrict__ src = (const float4*)data;
        float4* __restrict__ dst = (float4*)(out + A_ELEMS);
        const long long nvec = DATA_ELEMS / 4;
        for (; i < nvec; i += stride) dst[i] = src[i];
        return;
    }
    const int wave = (blockIdx.x - K1_COPY_BLOCKS) * 4 + (threadIdx.x >> 6);
    const int lane = threadIdx.x & 63;
    const int r = lane >> 2;      // patch row 0..15 (15 inactive)
    const int q = lane & 3;       // float4 quad in the 16-wide cell

    int b, y, x;
    long long delta;              // other cell = this cell + delta floats
    if (wave < NV_TOT) {
        const int e = wave;
        b = e / NV_PER_B; const int rem = e - b * NV_PER_B;
        y = rem >> 6; x = rem & 63;                 // edge (y,x)<->(y+1,x)
        delta = (long long)SCALE * WW;
    } else {
        const int e = wave - NV_TOT;
        b = e / NH_PER_B; const int rem = e - b * NH_PER_B;
        y = rem / 63; x = rem - y * 63;             // edge (y,x)<->(y,x+1)
        delta = SCALE;
    }

    const float* p0 = data + (((long long)(b * CC)) * HH + (long long)y * SCALE + r) * WW
                           + x * SCALE + q * 4;
    float s = 0.f;
    if (r < PP) {
        #pragma unroll
        for (int c = 0; c < CC; ++c) {
            const float* p = p0 + (long long)c * HH * WW;
            const float4 a  = *(const float4*)p;
            const float4 nb = *(const float4*)(p + delta);
            float d = fabsf(nb.x - a.x) + fabsf(nb.y - a.y) + fabsf(nb.z - a.z);
            if (q != 3) d += fabsf(nb.w - a.w);     // col 15 excluded
            s += d;
        }
    }
    #pragma unroll
    for (int off = 32; off; off >>= 1) s += __shfl_down(s, off, 64);
    if (lane == 0) ws[wave] = s;
}

// Kernel 2: pure-store row streamer. One wave per A-row; reads <=4 edge
// values from ws (uniform broadcast loads), then streams the 16 KB row of
// zeros. The <=4 iterations that contain an edge value are gated by
// readfirstlane-scalarized s_cmp branches, so the hot loop is store-only.
// NOTE: contributions must be MERGED (+=) into the float4, not assigned:
// left/right neighbors can share one float4 (n mod 4 in {1,2}).
__global__ __launch_bounds__(256) void row_kernel(const float* __restrict__ ws,
                                                  float* __restrict__ out) {
    const int wid  = blockIdx.x * 4 + (threadIdx.x >> 6);  // 0..16383
    const int lane = threadIdx.x & 63;
    const int b = wid >> 12;
    const int n = wid & (NNODE - 1);
    const int y = n >> 6, x = n & 63;

    const bool hasUp = y > 0, hasDown = y < NYG - 1;
    const bool hasLeft = x > 0, hasRight = x < NXG - 1;

    float vUp = 0.f, vDown = 0.f, vLeft = 0.f, vRight = 0.f;
    if (hasUp)    vUp    = ws[b * NV_PER_B + (y - 1) * 64 + x];
    if (hasDown)  vDown  = ws[b * NV_PER_B + y * 64 + x];
    if (hasLeft)  vLeft  = ws[NV_TOT + b * NH_PER_B + y * 63 + (x - 1)];
    if (hasRight) vRight = ws[NV_TOT + b * NH_PER_B + y * 63 + x];

    // target column coords -> (iteration k, lane l, component); wave-uniform,
    // scalarized so the hot loop compares against SGPRs.
    const int kUp    = __builtin_amdgcn_readfirstlane(hasUp    ? ((n - 64) >> 8) : -1);
    const int kDown  = __builtin_amdgcn_readfirstlane(hasDown  ? ((n + 64) >> 8) : -1);
    const int kLeft  = __builtin_amdgcn_readfirstlane(hasLeft  ? ((n - 1)  >> 8) : -1);
    const int kRight = __builtin_amdgcn_readfirstlane(hasRight ? ((n + 1)  >> 8) : -1);
    const int lUp    = __builtin_amdgcn_readfirstlane(((n - 64) >> 2) & 63);
    const int lDown  = __builtin_amdgcn_readfirstlane(((n + 64) >> 2) & 63);
    const int lLeft  = __builtin_amdgcn_readfirstlane(((n - 1)  >> 2) & 63);
    const int lRight = __builtin_amdgcn_readfirstlane(((n + 1)  >> 2) & 63);

    const int compUD = n & 3;            // (n±64)&3 == n&3
    const int compL  = (n - 1) & 3;
    const int compR  = (n + 1) & 3;

    float4 pUp, pDown, pLeft, pRight;
    pUp.x    = compUD == 0 ? vUp : 0.f;    pUp.y    = compUD == 1 ? vUp : 0.f;
    pUp.z    = compUD == 2 ? vUp : 0.f;    pUp.w    = compUD == 3 ? vUp : 0.f;
    pDown.x  = compUD == 0 ? vDown : 0.f;  pDown.y  = compUD == 1 ? vDown : 0.f;
    pDown.z  = compUD == 2 ? vDown : 0.f;  pDown.w  = compUD == 3 ? vDown : 0.f;
    pLeft.x  = compL == 0 ? vLeft : 0.f;   pLeft.y  = compL == 1 ? vLeft : 0.f;
    pLeft.z  = compL == 2 ? vLeft : 0.f;   pLeft.w  = compL == 3 ? vLeft : 0.f;
    pRight.x = compR == 0 ? vRight : 0.f;  pRight.y = compR == 1 ? vRight : 0.f;
    pRight.z = compR == 2 ? vRight : 0.f;  pRight.w = compR == 3 ? vRight : 0.f;

    float4* rowp = (float4*)(out + ((long long)b * NNODE + n) * NNODE);
    #pragma unroll
    for (int k = 0; k < 16; ++k) {
        float4 v = make_float4(0.f, 0.f, 0.f, 0.f);
        if (k == kUp)    { if (lane == lUp)    { v.x += pUp.x;    v.y += pUp.y;    v.z += pUp.z;    v.w += pUp.w;    } }
        if (k == kDown)  { if (lane == lDown)  { v.x += pDown.x;  v.y += pDown.y;  v.z += pDown.z;  v.w += pDown.w;  } }
        if (k == kLeft)  { if (lane == lLeft)  { v.x += pLeft.x;  v.y += pLeft.y;  v.z += pLeft.z;  v.w += pLeft.w;  } }
        if (k == kRight) { if (lane == lRight) { v.x += pRight.x; v.y += pRight.y; v.z += pRight.z; v.w += pRight.w; } }
        rowp[k * 64 + lane] = v;
    }
}

extern "C" void kernel_launch(void* const* d_in, const int* in_sizes, int n_in,
                              void* d_out, int out_size, void* d_ws, size_t ws_size,
                              hipStream_t stream) {
    const float* data = (const float*)d_in[0];
    float* out = (float*)d_out;
    float* ws  = (float*)d_ws;   // 32256 floats of edge values

    edge_copy_kernel<<<K1_COPY_BLOCKS + K1_EDGE_BLOCKS, 256, 0, stream>>>(data, ws, out);
    row_kernel<<<4096, 256, 0, stream>>>(ws, out);
}